// Round 1
// baseline (108.473 us; speedup 1.0000x reference)
//
#include <hip/hip_runtime.h>

// Quantizer forward: out = hard_q = nearest of 25 uniform levels in [-1, 1].
// (soft_q + stop_grad(hard_q - soft_q) has forward value == hard_q up to
//  ~1e-8 float rounding, far below the 2e-2 absmax threshold.)
//
// Correctness-critical: must match numpy's argmin over fl((x - levels[l])^2)
// with first-tie-wins. We pick a rounded candidate c, then re-decide among
// {c-1, c, c+1} using bit-exact numpy float32 arithmetic.

#define Z_LEVEL 25

__device__ __forceinline__ float level_of(int l) {
    // numpy: levels = arange(25, f32) * f32(2.0/24.0) + (-1.0f), mul/add
    // separately rounded (no fma contraction -> use _rn intrinsics).
    const float step = (float)(2.0 / 24.0);
    return __fadd_rn(__fmul_rn((float)l, step), -1.0f);
}

__device__ __forceinline__ float dist2(float x, int l) {
    float t = __fsub_rn(x, level_of(l));
    return __fmul_rn(t, t);
}

__device__ __forceinline__ float hard_quant(float x) {
    // Candidate nearest index (approximate is fine; window of 3 covers it).
    float t = fmaf(x, 12.0f, 12.0f);          // (x + 1) * 12
    int c = __float2int_rn(t);
    c = max(0, min(Z_LEVEL - 1, c));
    int l0 = max(0, c - 1);
    int l2 = min(Z_LEVEL - 1, c + 1);

    // numpy argmin semantics: scan ascending index, replace only if
    // strictly less -> lowest index wins ties.
    float d0 = dist2(x, l0);
    float d1 = dist2(x, c);
    float d2 = dist2(x, l2);

    int best = l0;
    float db = d0;
    if (d1 < db) { db = d1; best = c; }
    if (d2 < db) { best = l2; }
    return level_of(best);
}

__global__ void __launch_bounds__(256) quant_kernel(const float4* __restrict__ in,
                                                    float4* __restrict__ out,
                                                    int n4,
                                                    const float* __restrict__ in_s,
                                                    float* __restrict__ out_s,
                                                    int rem_base, int rem) {
    int i = blockIdx.x * blockDim.x + threadIdx.x;
    if (i < n4) {
        float4 v = in[i];
        float4 r;
        r.x = hard_quant(v.x);
        r.y = hard_quant(v.y);
        r.z = hard_quant(v.z);
        r.w = hard_quant(v.w);
        out[i] = r;
    }
    // Scalar tail (n not divisible by 4) — rem <= 3, handled by one thread.
    if (i == 0 && rem > 0) {
        for (int k = 0; k < rem; ++k)
            out_s[rem_base + k] = hard_quant(in_s[rem_base + k]);
    }
}

extern "C" void kernel_launch(void* const* d_in, const int* in_sizes, int n_in,
                              void* d_out, int out_size, void* d_ws, size_t ws_size,
                              hipStream_t stream) {
    const float* x = (const float*)d_in[0];
    float* out = (float*)d_out;
    int n = in_sizes[0];
    int n4 = n >> 2;
    int rem = n & 3;
    int rem_base = n4 << 2;
    int blocks = (n4 + 255) / 256;
    if (blocks < 1) blocks = 1;
    quant_kernel<<<blocks, 256, 0, stream>>>((const float4*)x, (float4*)out,
                                             n4, x, out, rem_base, rem);
}